// Round 1
// baseline (1645.897 us; speedup 1.0000x reference)
//
#include <hip/hip_runtime.h>
#include <cstdint>

#define DH 64
#define EPSV 1e-5f

__device__ __forceinline__ float atomAddF(float* p, float v) {
  return unsafeAtomicAdd(p, v);
}

__global__ void k_fill(float* __restrict__ p, float v, int n) {
  int i = blockIdx.x * blockDim.x + threadIdx.x;
  if (i < n) p[i] = v;
}

// deg[dst] += edge_weight  (deg pre-filled with 1.0 for self-loop)
__global__ void k_deg(const int* __restrict__ dst, const float* __restrict__ ew,
                      float* __restrict__ deg, int E_) {
  int e = blockIdx.x * blockDim.x + threadIdx.x;
  if (e < E_) atomAddF(&deg[dst[e]], ew[e]);
}

// in-place: deg -> dinv ; sc = 1/deg
__global__ void k_dinv(float* __restrict__ deg_dinv, float* __restrict__ sc, int n) {
  int i = blockIdx.x * blockDim.x + threadIdx.x;
  if (i < n) {
    float d = deg_dinv[i];
    deg_dinv[i] = rsqrtf(d);
    sc[i] = 1.0f / d;
  }
}

__global__ void k_norm(const int* __restrict__ src, const int* __restrict__ dst,
                       const float* __restrict__ ew, const float* __restrict__ dinv,
                       float* __restrict__ nrm, int E_) {
  int e = blockIdx.x * blockDim.x + threadIdx.x;
  if (e < E_) nrm[e] = ew[e] * dinv[src[e]] * dinv[dst[e]];
}

// C tile 128 rows x 64 cols, 256 threads, micro-tile 4x8 per thread.
// Writes H = A@W + bias and AGG = H * sc[row]  (self-loop init).
// Safe in-place (A == H): block reads only the rows it writes, all reads
// precede the epilogue.
__global__ __launch_bounds__(256) void k_gemm(
    const float* __restrict__ A, const float* __restrict__ W,
    const float* __restrict__ bias, const float* __restrict__ sc,
    float* __restrict__ H, float* __restrict__ AGG, int n, int K) {
  __shared__ float As[128][17];   // +1 pad breaks bank conflicts
  __shared__ float Bs[16][64];
  const int tid = threadIdx.x;
  const int tx = tid & 7;         // 8 col-groups of 8
  const int ty = tid >> 3;        // 32 row-groups of 4
  const int r0 = blockIdx.x * 128;
  float acc[4][8] = {};
  for (int kc = 0; kc < K; kc += 16) {
    for (int idx = tid; idx < 128 * 16; idx += 256) {
      int r = idx >> 4, c = idx & 15;
      int gr = r0 + r, gc = kc + c;
      As[r][c] = (gr < n && gc < K) ? A[(size_t)gr * K + gc] : 0.0f;
    }
    for (int idx = tid; idx < 16 * 64; idx += 256) {
      int r = idx >> 6, c = idx & 63;
      int gr = kc + r;
      Bs[r][c] = (gr < K) ? W[gr * DH + c] : 0.0f;
    }
    __syncthreads();
#pragma unroll
    for (int kk = 0; kk < 16; ++kk) {
      float a[4], b[8];
#pragma unroll
      for (int i = 0; i < 4; ++i) a[i] = As[ty * 4 + i][kk];
#pragma unroll
      for (int j = 0; j < 8; ++j) b[j] = Bs[kk][tx * 8 + j];
#pragma unroll
      for (int i = 0; i < 4; ++i)
#pragma unroll
        for (int j = 0; j < 8; ++j) acc[i][j] += a[i] * b[j];
    }
    __syncthreads();
  }
#pragma unroll
  for (int i = 0; i < 4; ++i) {
    int gr = r0 + ty * 4 + i;
    if (gr < n) {
      float s = sc[gr];
#pragma unroll
      for (int j = 0; j < 8; ++j) {
        int gc = tx * 8 + j;
        float h = acc[i][j] + bias[gc];
        H[(size_t)gr * DH + gc] = h;
        AGG[(size_t)gr * DH + gc] = h * s;
      }
    }
  }
}

// one wave (64 lanes) per edge: lane d handles feature d
__global__ __launch_bounds__(256) void k_scatter(
    const int* __restrict__ src, const int* __restrict__ dst,
    const float* __restrict__ nrm, const float* __restrict__ H,
    float* __restrict__ AGG, int E_) {
  int t = blockIdx.x * 256 + threadIdx.x;
  int e = t >> 6, d = t & 63;
  if (e < E_) {
    int s = src[e], q = dst[e];
    float v = nrm[e] * H[(size_t)s * DH + d];
    atomAddF(&AGG[(size_t)q * DH + d], v);
  }
}

// column sums & sumsq; thread's column = tid%64 (stride multiple of 64)
__global__ __launch_bounds__(256) void k_stats(const float* __restrict__ AGG,
                                               float* __restrict__ stats,
                                               size_t total) {
  float s = 0.f, ss = 0.f;
  size_t stride = (size_t)gridDim.x * 256;
  for (size_t i = blockIdx.x * 256ull + threadIdx.x; i < total; i += stride) {
    float v = AGG[i];
    s += v;
    ss += v * v;
  }
  __shared__ float sm[256], sm2[256];
  int tid = threadIdx.x;
  sm[tid] = s; sm2[tid] = ss;
  __syncthreads();
  if (tid < 128) { sm[tid] += sm[tid + 128]; sm2[tid] += sm2[tid + 128]; }
  __syncthreads();
  if (tid < 64) {
    atomAddF(&stats[tid], sm[tid] + sm[tid + 64]);
    atomAddF(&stats[DH + tid], sm2[tid] + sm2[tid + 64]);
  }
}

// OUT = relu((AGG - mean) * rsqrt(var+eps) * g + be), float4-vectorized
__global__ __launch_bounds__(256) void k_bnrelu(
    const float4* __restrict__ AGG4, const float* __restrict__ stats,
    const float* __restrict__ gam, const float* __restrict__ bet,
    float4* __restrict__ OUT4, size_t total4, float invN) {
  size_t stride = (size_t)gridDim.x * blockDim.x;
  size_t i0 = blockIdx.x * (size_t)blockDim.x + threadIdx.x;
  int cb = (int)((i0 * 4) & 63);  // constant per thread: stride*4 % 64 == 0
  float sa[4], sb[4];
#pragma unroll
  for (int j = 0; j < 4; ++j) {
    int c = cb + j;
    float mean = stats[c] * invN;
    float var = stats[DH + c] * invN - mean * mean;
    float a = rsqrtf(var + EPSV) * gam[c];
    sa[j] = a;
    sb[j] = bet[c] - mean * a;
  }
  for (size_t i = i0; i < total4; i += stride) {
    float4 v = AGG4[i];
    float4 o;
    o.x = fmaxf(v.x * sa[0] + sb[0], 0.f);
    o.y = fmaxf(v.y * sa[1] + sb[1], 0.f);
    o.z = fmaxf(v.z * sa[2] + sb[2], 0.f);
    o.w = fmaxf(v.w * sa[3] + sb[3], 0.f);
    OUT4[i] = o;
  }
}

// per-row dot(h, out_w) -> segment atomics (sum & count)
__global__ __launch_bounds__(256) void k_pool(
    const float* __restrict__ H, const float* __restrict__ ow,
    const int* __restrict__ batch, float* __restrict__ psum,
    float* __restrict__ pcnt, int n) {
  int t = blockIdx.x * 256 + threadIdx.x;
  int row = t >> 6, d = t & 63;
  if (row >= n) return;
  float v = H[(size_t)row * DH + d] * ow[d];
#pragma unroll
  for (int off = 32; off > 0; off >>= 1) v += __shfl_down(v, off, 64);
  if (d == 0) {
    int g = batch[row];
    atomAddF(&psum[g], v);
    atomAddF(&pcnt[g], 1.0f);
  }
}

__global__ void k_out(const float* __restrict__ psum, const float* __restrict__ pcnt,
                      const float* __restrict__ ob, float* __restrict__ out, int G_) {
  int g = blockIdx.x * blockDim.x + threadIdx.x;
  if (g < G_) out[g] = psum[g] / fmaxf(pcnt[g], 1.0f) + ob[0];
}

extern "C" void kernel_launch(void* const* d_in, const int* in_sizes, int n_in,
                              void* d_out, int out_size, void* d_ws, size_t ws_size,
                              hipStream_t stream) {
  const float* x    = (const float*)d_in[0];
  const int*   ei   = (const int*)d_in[1];
  const float* ew   = (const float*)d_in[2];
  const int*   batch= (const int*)d_in[3];
  const float* w0   = (const float*)d_in[4];
  const float* b0   = (const float*)d_in[5];
  const float* g0   = (const float*)d_in[6];
  const float* be0  = (const float*)d_in[7];
  const float* w1   = (const float*)d_in[8];
  const float* b1   = (const float*)d_in[9];
  const float* g1   = (const float*)d_in[10];
  const float* be1  = (const float*)d_in[11];
  const float* w2   = (const float*)d_in[12];
  const float* b2   = (const float*)d_in[13];
  const float* g2   = (const float*)d_in[14];
  const float* be2  = (const float*)d_in[15];
  const float* ow   = (const float*)d_in[16];
  const float* ob   = (const float*)d_in[17];

  const int N_  = in_sizes[3];
  const int E_  = in_sizes[2];
  const int DIN_= in_sizes[0] / N_;
  const int G_  = out_size;
  const int* srcIdx = ei;
  const int* dstIdx = ei + E_;

  float* ws = (float*)d_ws;
  size_t off = 0;
  float* deg_dinv = ws + off; off += N_;
  float* sc       = ws + off; off += N_;
  float* nrm      = ws + off; off += E_;
  float* hbuf     = ws + off; off += (size_t)N_ * DH;
  float* aggbuf   = ws + off; off += (size_t)N_ * DH;
  float* stats    = ws + off; off += 2 * DH;
  float* psum     = ws + off; off += G_;
  float* pcnt     = ws + off; off += G_;
  (void)ws_size; (void)n_in;

  // --- normalization precompute ---
  k_fill<<<(N_ + 255) / 256, 256, 0, stream>>>(deg_dinv, 1.0f, N_);
  k_deg<<<(E_ + 255) / 256, 256, 0, stream>>>(dstIdx, ew, deg_dinv, E_);
  k_dinv<<<(N_ + 255) / 256, 256, 0, stream>>>(deg_dinv, sc, N_);
  k_norm<<<(E_ + 255) / 256, 256, 0, stream>>>(srcIdx, dstIdx, ew, deg_dinv, nrm, E_);

  const float* Wl[3]  = {w0, w1, w2};
  const float* Bl[3]  = {b0, b1, b2};
  const float* Gl[3]  = {g0, g1, g2};
  const float* BeL[3] = {be0, be1, be2};

  const float* cur = x;
  int curK = DIN_;
  const float invN = 1.0f / (float)N_;
  const size_t total = (size_t)N_ * DH;

  for (int l = 0; l < 3; ++l) {
    k_gemm<<<(N_ + 127) / 128, 256, 0, stream>>>(cur, Wl[l], Bl[l], sc, hbuf, aggbuf, N_, curK);
    k_scatter<<<(int)(((size_t)E_ * 64 + 255) / 256), 256, 0, stream>>>(
        srcIdx, dstIdx, nrm, hbuf, aggbuf, E_);
    k_fill<<<1, 256, 0, stream>>>(stats, 0.0f, 2 * DH);
    k_stats<<<2048, 256, 0, stream>>>(aggbuf, stats, total);
    k_bnrelu<<<2048, 256, 0, stream>>>((const float4*)aggbuf, stats, Gl[l], BeL[l],
                                       (float4*)hbuf, total / 4, invN);
    cur = hbuf;
    curK = DH;
  }

  // --- pooling + head ---
  k_fill<<<(2 * G_ + 255) / 256, 256, 0, stream>>>(psum, 0.0f, 2 * G_);
  k_pool<<<(int)(((size_t)N_ * 64 + 255) / 256), 256, 0, stream>>>(hbuf, ow, batch, psum, pcnt, N_);
  k_out<<<(G_ + 255) / 256, 256, 0, stream>>>(psum, pcnt, ob, (float*)d_out, G_);
}

// Round 2
// 997.484 us; speedup vs baseline: 1.6500x; 1.6500x over previous
//
#include <hip/hip_runtime.h>
#include <cstdint>

#define DH 64
#define EPSV 1e-5f

__device__ __forceinline__ float atomAddF(float* p, float v) {
  return unsafeAtomicAdd(p, v);
}

__global__ void k_fill(float* __restrict__ p, float v, int n) {
  int i = blockIdx.x * blockDim.x + threadIdx.x;
  if (i < n) p[i] = v;
}

// deg[dst] += ew (deg pre-filled 1.0 for self-loop); cnt[dst]++ (histogram)
__global__ void k_degcnt(const int* __restrict__ dst, const float* __restrict__ ew,
                         float* __restrict__ deg, int* __restrict__ cnt, int E_) {
  int e = blockIdx.x * blockDim.x + threadIdx.x;
  if (e < E_) {
    int q = dst[e];
    atomAddF(&deg[q], ew[e]);
    atomicAdd(&cnt[q], 1);
  }
}

// in-place: deg -> dinv ; sc = 1/deg
__global__ void k_dinv(float* __restrict__ deg_dinv, float* __restrict__ sc, int n) {
  int i = blockIdx.x * blockDim.x + threadIdx.x;
  if (i < n) {
    float d = deg_dinv[i];
    deg_dinv[i] = rsqrtf(d);
    sc[i] = 1.0f / d;
  }
}

// ---- exclusive scan over n1 = N+1 values (value(i) = i<N ? cnt[i] : 0) ----
// 1024 elems per block, 256 threads x 4.
__global__ __launch_bounds__(256) void k_scan1(const int* __restrict__ cnt,
                                               int* __restrict__ out,
                                               int* __restrict__ bsums,
                                               int N_, int n1) {
  __shared__ int sm[256];
  const int t = threadIdx.x;
  const int base = blockIdx.x * 1024 + t * 4;
  int v[4], lsum = 0;
#pragma unroll
  for (int j = 0; j < 4; ++j) {
    int i = base + j;
    v[j] = (i < N_) ? cnt[i] : 0;
    lsum += v[j];
  }
  sm[t] = lsum;
  __syncthreads();
  for (int o = 1; o < 256; o <<= 1) {
    int x = (t >= o) ? sm[t - o] : 0;
    __syncthreads();
    if (t >= o) sm[t] += x;
    __syncthreads();
  }
  int run = sm[t] - lsum;  // exclusive prefix of this thread's chunk
#pragma unroll
  for (int j = 0; j < 4; ++j) {
    int i = base + j;
    if (i < n1) out[i] = run;
    run += v[j];
  }
  if (t == 255) bsums[blockIdx.x] = sm[255];
}

__global__ __launch_bounds__(256) void k_scan2(int* __restrict__ bsums, int nb) {
  __shared__ int sm[256];
  int t = threadIdx.x;
  int v = (t < nb) ? bsums[t] : 0;
  sm[t] = v;
  __syncthreads();
  for (int o = 1; o < 256; o <<= 1) {
    int x = (t >= o) ? sm[t - o] : 0;
    __syncthreads();
    if (t >= o) sm[t] += x;
    __syncthreads();
  }
  if (t < nb) bsums[t] = sm[t] - v;  // exclusive
}

__global__ void k_scan3(int* __restrict__ out, const int* __restrict__ bsums, int n1) {
  int i = blockIdx.x * blockDim.x + threadIdx.x;
  if (i < n1) out[i] += bsums[i >> 10];
}

// CSR reorder, fusing the norm computation. elist[p] = (src, norm)
__global__ void k_reorder(const int* __restrict__ src, const int* __restrict__ dst,
                          const float* __restrict__ ew, const float* __restrict__ dinv,
                          const int* __restrict__ rowstart, int* __restrict__ cursor,
                          uint2* __restrict__ elist, int E_) {
  int e = blockIdx.x * blockDim.x + threadIdx.x;
  if (e < E_) {
    int s = src[e], q = dst[e];
    float nm = ew[e] * dinv[s] * dinv[q];
    int p = rowstart[q] + atomicAdd(&cursor[q], 1);
    elist[p] = make_uint2((unsigned)s, __float_as_uint(nm));
  }
}

// C tile 128 rows x 64 cols, 256 threads, micro-tile 4x8 per thread.
// Safe in-place (A == H): block reads only the rows it writes.
__global__ __launch_bounds__(256) void k_gemm(
    const float* __restrict__ A, const float* __restrict__ W,
    const float* __restrict__ bias, float* __restrict__ H, int n, int K) {
  __shared__ float As[128][17];
  __shared__ float Bs[16][64];
  const int tid = threadIdx.x;
  const int tx = tid & 7;
  const int ty = tid >> 3;
  const int r0 = blockIdx.x * 128;
  float acc[4][8] = {};
  for (int kc = 0; kc < K; kc += 16) {
    for (int idx = tid; idx < 128 * 16; idx += 256) {
      int r = idx >> 4, c = idx & 15;
      int gr = r0 + r, gc = kc + c;
      As[r][c] = (gr < n && gc < K) ? A[(size_t)gr * K + gc] : 0.0f;
    }
    for (int idx = tid; idx < 16 * 64; idx += 256) {
      int r = idx >> 6, c = idx & 63;
      int gr = kc + r;
      Bs[r][c] = (gr < K) ? W[gr * DH + c] : 0.0f;
    }
    __syncthreads();
#pragma unroll
    for (int kk = 0; kk < 16; ++kk) {
      float a[4], b[8];
#pragma unroll
      for (int i = 0; i < 4; ++i) a[i] = As[ty * 4 + i][kk];
#pragma unroll
      for (int j = 0; j < 8; ++j) b[j] = Bs[kk][tx * 8 + j];
#pragma unroll
      for (int i = 0; i < 4; ++i)
#pragma unroll
        for (int j = 0; j < 8; ++j) acc[i][j] += a[i] * b[j];
    }
    __syncthreads();
  }
#pragma unroll
  for (int i = 0; i < 4; ++i) {
    int gr = r0 + ty * 4 + i;
    if (gr < n) {
#pragma unroll
      for (int j = 0; j < 8; ++j) {
        int gc = tx * 8 + j;
        H[(size_t)gr * DH + gc] = acc[i][j] + bias[gc];
      }
    }
  }
}

// Pull aggregation: one wave per dst row (grid-stride), lane d = feature d.
// acc init = self-loop H[row]*sc[row]; accumulate norm*H[src] over CSR edges.
// Fused BN stats: per-lane sum/sumsq over processed rows -> LDS reduce -> atomics.
__global__ __launch_bounds__(256) void k_gather(
    const uint2* __restrict__ elist, const int* __restrict__ rowstart,
    const float* __restrict__ H, const float* __restrict__ sc,
    float* __restrict__ AGG, float* __restrict__ stats, int n) {
  const int wid = threadIdx.x >> 6;
  const int d = threadIdx.x & 63;
  const int gw = blockIdx.x * 4 + wid;
  const int nw = gridDim.x * 4;
  float s = 0.f, ss = 0.f;
  for (int row = gw; row < n; row += nw) {
    int rs = rowstart[row], re = rowstart[row + 1];
    float acc = H[(size_t)row * DH + d] * sc[row];
    int i = rs;
    for (; i + 1 < re; i += 2) {
      uint2 p0 = elist[i];
      uint2 p1 = elist[i + 1];
      acc = fmaf(__uint_as_float(p0.y), H[(size_t)p0.x * DH + d], acc);
      acc = fmaf(__uint_as_float(p1.y), H[(size_t)p1.x * DH + d], acc);
    }
    if (i < re) {
      uint2 p0 = elist[i];
      acc = fmaf(__uint_as_float(p0.y), H[(size_t)p0.x * DH + d], acc);
    }
    AGG[(size_t)row * DH + d] = acc;
    s += acc;
    ss += acc * acc;
  }
  __shared__ float sm[4][DH], sm2[4][DH];
  sm[wid][d] = s;
  sm2[wid][d] = ss;
  __syncthreads();
  if (threadIdx.x < DH) {
    float a = sm[0][d] + sm[1][d] + sm[2][d] + sm[3][d];
    float b = sm2[0][d] + sm2[1][d] + sm2[2][d] + sm2[3][d];
    atomAddF(&stats[d], a);
    atomAddF(&stats[DH + d], b);
  }
}

// OUT = relu((AGG - mean) * rsqrt(var+eps) * g + be), float4-vectorized
__global__ __launch_bounds__(256) void k_bnrelu(
    const float4* __restrict__ AGG4, const float* __restrict__ stats,
    const float* __restrict__ gam, const float* __restrict__ bet,
    float4* __restrict__ OUT4, size_t total4, float invN) {
  size_t stride = (size_t)gridDim.x * blockDim.x;
  size_t i0 = blockIdx.x * (size_t)blockDim.x + threadIdx.x;
  int cb = (int)((i0 * 4) & 63);
  float sa[4], sb[4];
#pragma unroll
  for (int j = 0; j < 4; ++j) {
    int c = cb + j;
    float mean = stats[c] * invN;
    float var = stats[DH + c] * invN - mean * mean;
    float a = rsqrtf(var + EPSV) * gam[c];
    sa[j] = a;
    sb[j] = bet[c] - mean * a;
  }
  for (size_t i = i0; i < total4; i += stride) {
    float4 v = AGG4[i];
    float4 o;
    o.x = fmaxf(v.x * sa[0] + sb[0], 0.f);
    o.y = fmaxf(v.y * sa[1] + sb[1], 0.f);
    o.z = fmaxf(v.z * sa[2] + sb[2], 0.f);
    o.w = fmaxf(v.w * sa[3] + sb[3], 0.f);
    OUT4[i] = o;
  }
}

// per-row dot(h, out_w) -> segment atomics (sum & count)
__global__ __launch_bounds__(256) void k_pool(
    const float* __restrict__ H, const float* __restrict__ ow,
    const int* __restrict__ batch, float* __restrict__ psum,
    float* __restrict__ pcnt, int n) {
  int t = blockIdx.x * 256 + threadIdx.x;
  int row = t >> 6, d = t & 63;
  if (row >= n) return;
  float v = H[(size_t)row * DH + d] * ow[d];
#pragma unroll
  for (int off = 32; off > 0; off >>= 1) v += __shfl_down(v, off, 64);
  if (d == 0) {
    int g = batch[row];
    atomAddF(&psum[g], v);
    atomAddF(&pcnt[g], 1.0f);
  }
}

__global__ void k_out(const float* __restrict__ psum, const float* __restrict__ pcnt,
                      const float* __restrict__ ob, float* __restrict__ out, int G_) {
  int g = blockIdx.x * blockDim.x + threadIdx.x;
  if (g < G_) out[g] = psum[g] / fmaxf(pcnt[g], 1.0f) + ob[0];
}

extern "C" void kernel_launch(void* const* d_in, const int* in_sizes, int n_in,
                              void* d_out, int out_size, void* d_ws, size_t ws_size,
                              hipStream_t stream) {
  const float* x    = (const float*)d_in[0];
  const int*   ei   = (const int*)d_in[1];
  const float* ew   = (const float*)d_in[2];
  const int*   batch= (const int*)d_in[3];
  const float* w0   = (const float*)d_in[4];
  const float* b0   = (const float*)d_in[5];
  const float* g0   = (const float*)d_in[6];
  const float* be0  = (const float*)d_in[7];
  const float* w1   = (const float*)d_in[8];
  const float* b1   = (const float*)d_in[9];
  const float* g1   = (const float*)d_in[10];
  const float* be1  = (const float*)d_in[11];
  const float* w2   = (const float*)d_in[12];
  const float* b2   = (const float*)d_in[13];
  const float* g2   = (const float*)d_in[14];
  const float* be2  = (const float*)d_in[15];
  const float* ow   = (const float*)d_in[16];
  const float* ob   = (const float*)d_in[17];

  const int N_  = in_sizes[3];
  const int E_  = in_sizes[2];
  const int DIN_= in_sizes[0] / N_;
  const int G_  = out_size;
  const int* srcIdx = ei;
  const int* dstIdx = ei + E_;
  const int n1 = N_ + 1;

  float* ws = (float*)d_ws;
  size_t off = 0;
  // keep 8B alignment for elist: place it first
  uint2* elist    = (uint2*)(ws + off); off += (size_t)2 * E_;
  float* deg_dinv = ws + off; off += N_;
  float* sc       = ws + off; off += N_;
  int*   cnt      = (int*)(ws + off); off += N_;      // also cursor
  int*   rowstart = (int*)(ws + off); off += n1 + 1;
  int*   bsums    = (int*)(ws + off); off += 256;
  float* hbuf     = ws + off; off += (size_t)N_ * DH;
  float* aggbuf   = ws + off; off += (size_t)N_ * DH;
  float* stats    = ws + off; off += 2 * DH;
  float* psum     = ws + off; off += G_;
  float* pcnt     = ws + off; off += G_;
  (void)ws_size; (void)n_in;

  // --- degree + histogram ---
  k_fill<<<(N_ + 255) / 256, 256, 0, stream>>>(deg_dinv, 1.0f, N_);
  k_fill<<<(N_ + 255) / 256, 256, 0, stream>>>((float*)cnt, 0.0f, N_);
  k_degcnt<<<(E_ + 255) / 256, 256, 0, stream>>>(dstIdx, ew, deg_dinv, cnt, E_);
  k_dinv<<<(N_ + 255) / 256, 256, 0, stream>>>(deg_dinv, sc, N_);

  // --- exclusive scan cnt -> rowstart (n1 entries) ---
  const int nb = (n1 + 1023) / 1024;
  k_scan1<<<nb, 256, 0, stream>>>(cnt, rowstart, bsums, N_, n1);
  k_scan2<<<1, 256, 0, stream>>>(bsums, nb);
  k_scan3<<<(n1 + 255) / 256, 256, 0, stream>>>(rowstart, bsums, n1);

  // --- reorder edges into CSR, cnt reused as cursor ---
  k_fill<<<(N_ + 255) / 256, 256, 0, stream>>>((float*)cnt, 0.0f, N_);
  k_reorder<<<(E_ + 255) / 256, 256, 0, stream>>>(srcIdx, dstIdx, ew, deg_dinv,
                                                  rowstart, cnt, elist, E_);

  const float* Wl[3]  = {w0, w1, w2};
  const float* Bl[3]  = {b0, b1, b2};
  const float* Gl[3]  = {g0, g1, g2};
  const float* BeL[3] = {be0, be1, be2};

  const float* cur = x;
  int curK = DIN_;
  const float invN = 1.0f / (float)N_;
  const size_t total = (size_t)N_ * DH;

  for (int l = 0; l < 3; ++l) {
    k_gemm<<<(N_ + 127) / 128, 256, 0, stream>>>(cur, Wl[l], Bl[l], hbuf, N_, curK);
    k_fill<<<1, 256, 0, stream>>>(stats, 0.0f, 2 * DH);
    k_gather<<<2048, 256, 0, stream>>>(elist, rowstart, hbuf, sc, aggbuf, stats, N_);
    k_bnrelu<<<2048, 256, 0, stream>>>((const float4*)aggbuf, stats, Gl[l], BeL[l],
                                       (float4*)hbuf, total / 4, invN);
    cur = hbuf;
    curK = DH;
  }

  // --- pooling + head ---
  k_fill<<<(2 * G_ + 255) / 256, 256, 0, stream>>>(psum, 0.0f, 2 * G_);
  k_pool<<<(int)(((size_t)N_ * 64 + 255) / 256), 256, 0, stream>>>(hbuf, ow, batch, psum, pcnt, N_);
  k_out<<<(G_ + 255) / 256, 256, 0, stream>>>(psum, pcnt, ob, (float*)d_out, G_);
}

// Round 3
// 835.941 us; speedup vs baseline: 1.9689x; 1.1932x over previous
//
#include <hip/hip_runtime.h>
#include <cstdint>

#define DH 64
#define EPSV 1e-5f

__device__ __forceinline__ float atomAddF(float* p, float v) {
  return unsafeAtomicAdd(p, v);
}

__global__ void k_fill(float* __restrict__ p, float v, int n) {
  int i = blockIdx.x * blockDim.x + threadIdx.x;
  if (i < n) p[i] = v;
}

// deg[dst] += ew (deg pre-filled 1.0 for self-loop); cnt[dst]++ (histogram)
__global__ void k_degcnt(const int* __restrict__ dst, const float* __restrict__ ew,
                         float* __restrict__ deg, int* __restrict__ cnt, int E_) {
  int e = blockIdx.x * blockDim.x + threadIdx.x;
  if (e < E_) {
    int q = dst[e];
    atomAddF(&deg[q], ew[e]);
    atomicAdd(&cnt[q], 1);
  }
}

// in-place: deg -> dinv ; sc = 1/deg
__global__ void k_dinv(float* __restrict__ deg_dinv, float* __restrict__ sc, int n) {
  int i = blockIdx.x * blockDim.x + threadIdx.x;
  if (i < n) {
    float d = deg_dinv[i];
    deg_dinv[i] = rsqrtf(d);
    sc[i] = 1.0f / d;
  }
}

// ---- exclusive scan over n1 = N+1 values (value(i) = i<N ? cnt[i] : 0) ----
__global__ __launch_bounds__(256) void k_scan1(const int* __restrict__ cnt,
                                               int* __restrict__ out,
                                               int* __restrict__ bsums,
                                               int N_, int n1) {
  __shared__ int sm[256];
  const int t = threadIdx.x;
  const int base = blockIdx.x * 1024 + t * 4;
  int v[4], lsum = 0;
#pragma unroll
  for (int j = 0; j < 4; ++j) {
    int i = base + j;
    v[j] = (i < N_) ? cnt[i] : 0;
    lsum += v[j];
  }
  sm[t] = lsum;
  __syncthreads();
  for (int o = 1; o < 256; o <<= 1) {
    int x = (t >= o) ? sm[t - o] : 0;
    __syncthreads();
    if (t >= o) sm[t] += x;
    __syncthreads();
  }
  int run = sm[t] - lsum;
#pragma unroll
  for (int j = 0; j < 4; ++j) {
    int i = base + j;
    if (i < n1) out[i] = run;
    run += v[j];
  }
  if (t == 255) bsums[blockIdx.x] = sm[255];
}

__global__ __launch_bounds__(256) void k_scan2(int* __restrict__ bsums, int nb) {
  __shared__ int sm[256];
  int t = threadIdx.x;
  int v = (t < nb) ? bsums[t] : 0;
  sm[t] = v;
  __syncthreads();
  for (int o = 1; o < 256; o <<= 1) {
    int x = (t >= o) ? sm[t - o] : 0;
    __syncthreads();
    if (t >= o) sm[t] += x;
    __syncthreads();
  }
  if (t < nb) bsums[t] = sm[t] - v;
}

__global__ void k_scan3(int* __restrict__ out, const int* __restrict__ bsums, int n1) {
  int i = blockIdx.x * blockDim.x + threadIdx.x;
  if (i < n1) out[i] += bsums[i >> 10];
}

// CSR reorder, fusing the norm computation. elist[p] = (src, norm)
__global__ void k_reorder(const int* __restrict__ src, const int* __restrict__ dst,
                          const float* __restrict__ ew, const float* __restrict__ dinv,
                          const int* __restrict__ rowstart, int* __restrict__ cursor,
                          uint2* __restrict__ elist, int E_) {
  int e = blockIdx.x * blockDim.x + threadIdx.x;
  if (e < E_) {
    int s = src[e], q = dst[e];
    float nm = ew[e] * dinv[s] * dinv[q];
    int p = rowstart[q] + atomicAdd(&cursor[q], 1);
    elist[p] = make_uint2((unsigned)s, __float_as_uint(nm));
  }
}

// graph boundary detection on sorted batch: gstart[g] for g in [0,G]
__global__ void k_gbound(const int* __restrict__ batch, int* __restrict__ gstart,
                         int N_, int G_) {
  int i = blockIdx.x * blockDim.x + threadIdx.x;
  if (i >= N_) return;
  int b = batch[i];
  if (i == 0) {
    for (int g = 0; g <= b; ++g) gstart[g] = 0;
  }
  int nb = (i + 1 < N_) ? batch[i + 1] : G_;
  for (int g = b + 1; g <= nb; ++g) gstart[g] = i + 1;
}

// C tile 128 rows x 64 cols, 256 threads, micro-tile 4x8 per thread.
// Safe in-place (A == H): block reads only the rows it writes.
__global__ __launch_bounds__(256) void k_gemm(
    const float* __restrict__ A, const float* __restrict__ W,
    const float* __restrict__ bias, float* __restrict__ H, int n, int K) {
  __shared__ float As[128][17];
  __shared__ float Bs[16][64];
  const int tid = threadIdx.x;
  const int tx = tid & 7;
  const int ty = tid >> 3;
  const int r0 = blockIdx.x * 128;
  float acc[4][8] = {};
  for (int kc = 0; kc < K; kc += 16) {
    for (int idx = tid; idx < 128 * 16; idx += 256) {
      int r = idx >> 4, c = idx & 15;
      int gr = r0 + r, gc = kc + c;
      As[r][c] = (gr < n && gc < K) ? A[(size_t)gr * K + gc] : 0.0f;
    }
    for (int idx = tid; idx < 16 * 64; idx += 256) {
      int r = idx >> 6, c = idx & 63;
      int gr = kc + r;
      Bs[r][c] = (gr < K) ? W[gr * DH + c] : 0.0f;
    }
    __syncthreads();
#pragma unroll
    for (int kk = 0; kk < 16; ++kk) {
      float a[4], b[8];
#pragma unroll
      for (int i = 0; i < 4; ++i) a[i] = As[ty * 4 + i][kk];
#pragma unroll
      for (int j = 0; j < 8; ++j) b[j] = Bs[kk][tx * 8 + j];
#pragma unroll
      for (int i = 0; i < 4; ++i)
#pragma unroll
        for (int j = 0; j < 8; ++j) acc[i][j] += a[i] * b[j];
    }
    __syncthreads();
  }
#pragma unroll
  for (int i = 0; i < 4; ++i) {
    int gr = r0 + ty * 4 + i;
    if (gr < n) {
#pragma unroll
      for (int j = 0; j < 8; ++j) {
        int gc = tx * 8 + j;
        H[(size_t)gr * DH + gc] = acc[i][j] + bias[gc];
      }
    }
  }
}

// Pull aggregation: one wave per dst row (grid-stride), lane d = feature d.
// Fused BN stats accumulation.
__global__ __launch_bounds__(256) void k_gather(
    const uint2* __restrict__ elist, const int* __restrict__ rowstart,
    const float* __restrict__ H, const float* __restrict__ sc,
    float* __restrict__ AGG, float* __restrict__ stats, int n) {
  const int wid = threadIdx.x >> 6;
  const int d = threadIdx.x & 63;
  const int gw = blockIdx.x * 4 + wid;
  const int nw = gridDim.x * 4;
  float s = 0.f, ss = 0.f;
  for (int row = gw; row < n; row += nw) {
    int rs = rowstart[row], re = rowstart[row + 1];
    float acc = H[(size_t)row * DH + d] * sc[row];
    int i = rs;
    for (; i + 1 < re; i += 2) {
      uint2 p0 = elist[i];
      uint2 p1 = elist[i + 1];
      acc = fmaf(__uint_as_float(p0.y), H[(size_t)p0.x * DH + d], acc);
      acc = fmaf(__uint_as_float(p1.y), H[(size_t)p1.x * DH + d], acc);
    }
    if (i < re) {
      uint2 p0 = elist[i];
      acc = fmaf(__uint_as_float(p0.y), H[(size_t)p0.x * DH + d], acc);
    }
    AGG[(size_t)row * DH + d] = acc;
    s += acc;
    ss += acc * acc;
  }
  __shared__ float sm[4][DH], sm2[4][DH];
  sm[wid][d] = s;
  sm2[wid][d] = ss;
  __syncthreads();
  if (threadIdx.x < DH) {
    float a = sm[0][d] + sm[1][d] + sm[2][d] + sm[3][d];
    float b = sm2[0][d] + sm2[1][d] + sm2[2][d] + sm2[3][d];
    atomAddF(&stats[d], a);
    atomAddF(&stats[DH + d], b);
  }
}

// OUT = relu((AGG - mean) * rsqrt(var+eps) * g + be), float4-vectorized
__global__ __launch_bounds__(256) void k_bnrelu(
    const float4* __restrict__ AGG4, const float* __restrict__ stats,
    const float* __restrict__ gam, const float* __restrict__ bet,
    float4* __restrict__ OUT4, size_t total4, float invN) {
  size_t stride = (size_t)gridDim.x * blockDim.x;
  size_t i0 = blockIdx.x * (size_t)blockDim.x + threadIdx.x;
  int cb = (int)((i0 * 4) & 63);
  float sa[4], sb[4];
#pragma unroll
  for (int j = 0; j < 4; ++j) {
    int c = cb + j;
    float mean = stats[c] * invN;
    float var = stats[DH + c] * invN - mean * mean;
    float a = rsqrtf(var + EPSV) * gam[c];
    sa[j] = a;
    sb[j] = bet[c] - mean * a;
  }
  for (size_t i = i0; i < total4; i += stride) {
    float4 v = AGG4[i];
    float4 o;
    o.x = fmaxf(v.x * sa[0] + sb[0], 0.f);
    o.y = fmaxf(v.y * sa[1] + sb[1], 0.f);
    o.z = fmaxf(v.z * sa[2] + sb[2], 0.f);
    o.w = fmaxf(v.w * sa[3] + sb[3], 0.f);
    OUT4[i] = o;
  }
}

// fused mean-pool + head: one block per graph, rows [gstart[g], gstart[g+1])
// out[g] = (sum over rows of h.ow)/cnt + ob   (no atomics)
__global__ __launch_bounds__(256) void k_poolhead(
    const float* __restrict__ H, const float* __restrict__ ow,
    const int* __restrict__ gstart, const float* __restrict__ ob,
    float* __restrict__ out) {
  const int g = blockIdx.x;
  const int gs = gstart[g], ge = gstart[g + 1];
  const int wid = threadIdx.x >> 6;
  const int d = threadIdx.x & 63;
  const float w = ow[d];
  float acc = 0.f;
  for (int row = gs + wid; row < ge; row += 4)
    acc += H[(size_t)row * DH + d] * w;
#pragma unroll
  for (int off = 32; off > 0; off >>= 1) acc += __shfl_down(acc, off, 64);
  __shared__ float sm[4];
  if (d == 0) sm[wid] = acc;
  __syncthreads();
  if (threadIdx.x == 0) {
    float s = sm[0] + sm[1] + sm[2] + sm[3];
    float cnt = (float)(ge - gs);
    out[g] = s / fmaxf(cnt, 1.0f) + ob[0];
  }
}

extern "C" void kernel_launch(void* const* d_in, const int* in_sizes, int n_in,
                              void* d_out, int out_size, void* d_ws, size_t ws_size,
                              hipStream_t stream) {
  const float* x    = (const float*)d_in[0];
  const int*   ei   = (const int*)d_in[1];
  const float* ew   = (const float*)d_in[2];
  const int*   batch= (const int*)d_in[3];
  const float* w0   = (const float*)d_in[4];
  const float* b0   = (const float*)d_in[5];
  const float* g0   = (const float*)d_in[6];
  const float* be0  = (const float*)d_in[7];
  const float* w1   = (const float*)d_in[8];
  const float* b1   = (const float*)d_in[9];
  const float* g1   = (const float*)d_in[10];
  const float* be1  = (const float*)d_in[11];
  const float* w2   = (const float*)d_in[12];
  const float* b2   = (const float*)d_in[13];
  const float* g2   = (const float*)d_in[14];
  const float* be2  = (const float*)d_in[15];
  const float* ow   = (const float*)d_in[16];
  const float* ob   = (const float*)d_in[17];

  const int N_  = in_sizes[3];
  const int E_  = in_sizes[2];
  const int DIN_= in_sizes[0] / N_;
  const int G_  = out_size;
  const int* srcIdx = ei;
  const int* dstIdx = ei + E_;
  const int n1 = N_ + 1;

  float* ws = (float*)d_ws;
  size_t off = 0;
  uint2* elist    = (uint2*)(ws + off); off += (size_t)2 * E_;
  float* deg_dinv = ws + off; off += N_;
  float* sc       = ws + off; off += N_;
  int*   cnt      = (int*)(ws + off); off += N_;      // also cursor
  int*   rowstart = (int*)(ws + off); off += n1 + 1;
  int*   bsums    = (int*)(ws + off); off += 256;
  int*   gstart   = (int*)(ws + off); off += G_ + 1;
  float* hbuf     = ws + off; off += (size_t)N_ * DH;
  float* aggbuf   = ws + off; off += (size_t)N_ * DH;
  float* stats    = ws + off; off += 2 * DH;
  (void)ws_size; (void)n_in;

  // --- degree + histogram ---
  k_fill<<<(N_ + 255) / 256, 256, 0, stream>>>(deg_dinv, 1.0f, N_);
  k_fill<<<(N_ + 255) / 256, 256, 0, stream>>>((float*)cnt, 0.0f, N_);
  k_degcnt<<<(E_ + 255) / 256, 256, 0, stream>>>(dstIdx, ew, deg_dinv, cnt, E_);
  k_dinv<<<(N_ + 255) / 256, 256, 0, stream>>>(deg_dinv, sc, N_);

  // --- exclusive scan cnt -> rowstart ---
  const int nb = (n1 + 1023) / 1024;
  k_scan1<<<nb, 256, 0, stream>>>(cnt, rowstart, bsums, N_, n1);
  k_scan2<<<1, 256, 0, stream>>>(bsums, nb);
  k_scan3<<<(n1 + 255) / 256, 256, 0, stream>>>(rowstart, bsums, n1);

  // --- reorder edges into CSR, cnt reused as cursor ---
  k_fill<<<(N_ + 255) / 256, 256, 0, stream>>>((float*)cnt, 0.0f, N_);
  k_reorder<<<(E_ + 255) / 256, 256, 0, stream>>>(srcIdx, dstIdx, ew, deg_dinv,
                                                  rowstart, cnt, elist, E_);

  // --- graph boundaries for pooling ---
  k_gbound<<<(N_ + 255) / 256, 256, 0, stream>>>(batch, gstart, N_, G_);

  const float* Wl[3]  = {w0, w1, w2};
  const float* Bl[3]  = {b0, b1, b2};
  const float* Gl[3]  = {g0, g1, g2};
  const float* BeL[3] = {be0, be1, be2};

  const float* cur = x;
  int curK = DIN_;
  const float invN = 1.0f / (float)N_;
  const size_t total = (size_t)N_ * DH;

  for (int l = 0; l < 3; ++l) {
    k_gemm<<<(N_ + 127) / 128, 256, 0, stream>>>(cur, Wl[l], Bl[l], hbuf, N_, curK);
    k_fill<<<1, 256, 0, stream>>>(stats, 0.0f, 2 * DH);
    k_gather<<<2048, 256, 0, stream>>>(elist, rowstart, hbuf, sc, aggbuf, stats, N_);
    k_bnrelu<<<2048, 256, 0, stream>>>((const float4*)aggbuf, stats, Gl[l], BeL[l],
                                       (float4*)hbuf, total / 4, invN);
    cur = hbuf;
    curK = DH;
  }

  // --- fused pooling + head ---
  k_poolhead<<<G_, 256, 0, stream>>>(hbuf, ow, gstart, ob, (float*)d_out);
}

// Round 4
// 704.921 us; speedup vs baseline: 2.3349x; 1.1859x over previous
//
#include <hip/hip_runtime.h>
#include <hip/hip_fp16.h>
#include <cstdint>

#define DH 64
#define EPSV 1e-5f

__device__ __forceinline__ float atomAddF(float* p, float v) {
  return unsafeAtomicAdd(p, v);
}

__global__ void k_fill(float* __restrict__ p, float v, size_t n) {
  size_t i = blockIdx.x * (size_t)blockDim.x + threadIdx.x;
  if (i < n) p[i] = v;
}

// deg[dst] += ew (deg pre-filled 1.0 for self-loop); cnt[dst]++ (histogram)
__global__ void k_degcnt(const int* __restrict__ dst, const float* __restrict__ ew,
                         float* __restrict__ deg, int* __restrict__ cnt, int E_) {
  int e = blockIdx.x * blockDim.x + threadIdx.x;
  if (e < E_) {
    int q = dst[e];
    atomAddF(&deg[q], ew[e]);
    atomicAdd(&cnt[q], 1);
  }
}

// in-place: deg -> dinv ; sc = 1/deg
__global__ void k_dinv(float* __restrict__ deg_dinv, float* __restrict__ sc, int n) {
  int i = blockIdx.x * blockDim.x + threadIdx.x;
  if (i < n) {
    float d = deg_dinv[i];
    deg_dinv[i] = rsqrtf(d);
    sc[i] = 1.0f / d;
  }
}

// ---- exclusive scan over n1 = N+1 values; value(i) = i<N ? pad8(cnt[i]) : 0 ----
__global__ __launch_bounds__(256) void k_scan1(const int* __restrict__ cnt,
                                               int* __restrict__ out,
                                               int* __restrict__ bsums,
                                               int N_, int n1) {
  __shared__ int sm[256];
  const int t = threadIdx.x;
  const int base = blockIdx.x * 1024 + t * 4;
  int v[4], lsum = 0;
#pragma unroll
  for (int j = 0; j < 4; ++j) {
    int i = base + j;
    v[j] = (i < N_) ? ((cnt[i] + 7) & ~7) : 0;   // pad rows to multiple of 8
    lsum += v[j];
  }
  sm[t] = lsum;
  __syncthreads();
  for (int o = 1; o < 256; o <<= 1) {
    int x = (t >= o) ? sm[t - o] : 0;
    __syncthreads();
    if (t >= o) sm[t] += x;
    __syncthreads();
  }
  int run = sm[t] - lsum;
#pragma unroll
  for (int j = 0; j < 4; ++j) {
    int i = base + j;
    if (i < n1) out[i] = run;
    run += v[j];
  }
  if (t == 255) bsums[blockIdx.x] = sm[255];
}

__global__ __launch_bounds__(256) void k_scan2(int* __restrict__ bsums, int nb) {
  __shared__ int sm[256];
  int t = threadIdx.x;
  int v = (t < nb) ? bsums[t] : 0;
  sm[t] = v;
  __syncthreads();
  for (int o = 1; o < 256; o <<= 1) {
    int x = (t >= o) ? sm[t - o] : 0;
    __syncthreads();
    if (t >= o) sm[t] += x;
    __syncthreads();
  }
  if (t < nb) bsums[t] = sm[t] - v;
}

__global__ void k_scan3(int* __restrict__ out, const int* __restrict__ bsums, int n1) {
  int i = blockIdx.x * blockDim.x + threadIdx.x;
  if (i < n1) out[i] += bsums[i >> 10];
}

// CSR reorder, fusing the norm computation. elist[p] = (src, norm)
__global__ void k_reorder(const int* __restrict__ src, const int* __restrict__ dst,
                          const float* __restrict__ ew, const float* __restrict__ dinv,
                          const int* __restrict__ rowstart, int* __restrict__ cursor,
                          uint2* __restrict__ elist, int E_) {
  int e = blockIdx.x * blockDim.x + threadIdx.x;
  if (e < E_) {
    int s = src[e], q = dst[e];
    float nm = ew[e] * dinv[s] * dinv[q];
    int p = rowstart[q] + atomicAdd(&cursor[q], 1);
    elist[p] = make_uint2((unsigned)s, __float_as_uint(nm));
  }
}

// graph boundary detection on sorted batch: gstart[g] for g in [0,G]
__global__ void k_gbound(const int* __restrict__ batch, int* __restrict__ gstart,
                         int N_, int G_) {
  int i = blockIdx.x * blockDim.x + threadIdx.x;
  if (i >= N_) return;
  int b = batch[i];
  if (i == 0) {
    for (int g = 0; g <= b; ++g) gstart[g] = 0;
  }
  int nb = (i + 1 < N_) ? batch[i + 1] : G_;
  for (int g = b + 1; g <= nb; ++g) gstart[g] = i + 1;
}

// C tile 128 rows x 64 cols, 256 threads, micro-tile 4x8 per thread.
// Optionally applies BN(prev layer)+ReLU to A elements while loading.
// Epilogue writes fp16 H only.
__global__ __launch_bounds__(256) void k_gemm(
    const float* __restrict__ A, const float* __restrict__ W,
    const float* __restrict__ bias, const float* __restrict__ stats,
    const float* __restrict__ gam, const float* __restrict__ bet,
    __half* __restrict__ Hh, int n, int K, int fuse, float invN) {
  __shared__ float As[128][17];
  __shared__ float Bs[16][64];
  __shared__ float saL[DH], sbL[DH];
  const int tid = threadIdx.x;
  const int tx = tid & 7;
  const int ty = tid >> 3;
  const int r0 = blockIdx.x * 128;
  if (fuse && tid < DH) {
    float mean = stats[tid] * invN;
    float var = stats[DH + tid] * invN - mean * mean;
    float a = rsqrtf(var + EPSV) * gam[tid];
    saL[tid] = a;
    sbL[tid] = bet[tid] - mean * a;
  }
  if (fuse) __syncthreads();
  float acc[4][8] = {};
  for (int kc = 0; kc < K; kc += 16) {
    for (int idx = tid; idx < 128 * 16; idx += 256) {
      int r = idx >> 4, c = idx & 15;
      int gr = r0 + r, gc = kc + c;
      float v = (gr < n && gc < K) ? A[(size_t)gr * K + gc] : 0.0f;
      if (fuse) v = fmaxf(v * saL[gc] + sbL[gc], 0.0f);
      As[r][c] = v;
    }
    for (int idx = tid; idx < 16 * 64; idx += 256) {
      int r = idx >> 6, c = idx & 63;
      int gr = kc + r;
      Bs[r][c] = (gr < K) ? W[gr * DH + c] : 0.0f;
    }
    __syncthreads();
#pragma unroll
    for (int kk = 0; kk < 16; ++kk) {
      float a[4], b[8];
#pragma unroll
      for (int i = 0; i < 4; ++i) a[i] = As[ty * 4 + i][kk];
#pragma unroll
      for (int j = 0; j < 8; ++j) b[j] = Bs[kk][tx * 8 + j];
#pragma unroll
      for (int i = 0; i < 4; ++i)
#pragma unroll
        for (int j = 0; j < 8; ++j) acc[i][j] += a[i] * b[j];
    }
    __syncthreads();
  }
#pragma unroll
  for (int i = 0; i < 4; ++i) {
    int gr = r0 + ty * 4 + i;
    if (gr < n) {
      float h[8];
#pragma unroll
      for (int j = 0; j < 8; ++j) h[j] = acc[i][j] + bias[tx * 8 + j];
      uint4 o;
      o.x = (unsigned)__half_as_ushort(__float2half(h[0])) |
            ((unsigned)__half_as_ushort(__float2half(h[1])) << 16);
      o.y = (unsigned)__half_as_ushort(__float2half(h[2])) |
            ((unsigned)__half_as_ushort(__float2half(h[3])) << 16);
      o.z = (unsigned)__half_as_ushort(__float2half(h[4])) |
            ((unsigned)__half_as_ushort(__float2half(h[5])) << 16);
      o.w = (unsigned)__half_as_ushort(__float2half(h[6])) |
            ((unsigned)__half_as_ushort(__float2half(h[7])) << 16);
      *reinterpret_cast<uint4*>(&Hh[(size_t)gr * DH + tx * 8]) = o;
    }
  }
}

// Pull aggregation: one wave per dst row (grid-stride), lane d = feature d.
// Rows padded to multiples of 8 edges (pad = src 0, norm 0) -> tail-free,
// 8 independent gathers in flight. fp16 gather operand. Fused BN stats.
__global__ __launch_bounds__(256) void k_gather(
    const uint2* __restrict__ elist, const int* __restrict__ rowstart,
    const __half* __restrict__ Hh, const float* __restrict__ sc,
    float* __restrict__ AGG, float* __restrict__ stats, int n) {
  const int wid = threadIdx.x >> 6;
  const int d = threadIdx.x & 63;
  const int gw = blockIdx.x * 4 + wid;
  const int nw = gridDim.x * 4;
  float s = 0.f, ss = 0.f;
  for (int row = gw; row < n; row += nw) {
    int rs = rowstart[row], re = rowstart[row + 1];
    float acc = __half2float(Hh[(size_t)row * DH + d]) * sc[row];
    for (int i = rs; i < re; i += 8) {
      uint2 e[8];
#pragma unroll
      for (int j = 0; j < 8; ++j) e[j] = elist[i + j];
      float v[8];
#pragma unroll
      for (int j = 0; j < 8; ++j)
        v[j] = __half2float(Hh[(size_t)e[j].x * DH + d]);
#pragma unroll
      for (int j = 0; j < 8; ++j)
        acc = fmaf(__uint_as_float(e[j].y), v[j], acc);
    }
    AGG[(size_t)row * DH + d] = acc;
    s += acc;
    ss += acc * acc;
  }
  __shared__ float sm[4][DH], sm2[4][DH];
  sm[wid][d] = s;
  sm2[wid][d] = ss;
  __syncthreads();
  if (threadIdx.x < DH) {
    float a = sm[0][d] + sm[1][d] + sm[2][d] + sm[3][d];
    float b = sm2[0][d] + sm2[1][d] + sm2[2][d] + sm2[3][d];
    atomAddF(&stats[d], a);
    atomAddF(&stats[DH + d], b);
  }
}

// fused BN+ReLU+mean-pool+head: one block per graph.
// out[g] = mean_rows( relu(bn(AGG[row])).ow ) + ob
__global__ __launch_bounds__(256) void k_poolhead(
    const float* __restrict__ AGG, const float* __restrict__ stats,
    const float* __restrict__ gam, const float* __restrict__ bet,
    const float* __restrict__ ow, const int* __restrict__ gstart,
    const float* __restrict__ ob, float* __restrict__ out, float invN) {
  const int g = blockIdx.x;
  const int gs = gstart[g], ge = gstart[g + 1];
  const int wid = threadIdx.x >> 6;
  const int d = threadIdx.x & 63;
  float mean = stats[d] * invN;
  float var = stats[DH + d] * invN - mean * mean;
  float sa = rsqrtf(var + EPSV) * gam[d];
  float sb = bet[d] - mean * sa;
  const float w = ow[d];
  float acc = 0.f;
  for (int row = gs + wid; row < ge; row += 4)
    acc += fmaxf(AGG[(size_t)row * DH + d] * sa + sb, 0.f) * w;
#pragma unroll
  for (int off = 32; off > 0; off >>= 1) acc += __shfl_down(acc, off, 64);
  __shared__ float sm[4];
  if (d == 0) sm[wid] = acc;
  __syncthreads();
  if (threadIdx.x == 0) {
    float s = sm[0] + sm[1] + sm[2] + sm[3];
    float cnt = (float)(ge - gs);
    out[g] = s / fmaxf(cnt, 1.0f) + ob[0];
  }
}

extern "C" void kernel_launch(void* const* d_in, const int* in_sizes, int n_in,
                              void* d_out, int out_size, void* d_ws, size_t ws_size,
                              hipStream_t stream) {
  const float* x    = (const float*)d_in[0];
  const int*   ei   = (const int*)d_in[1];
  const float* ew   = (const float*)d_in[2];
  const int*   batch= (const int*)d_in[3];
  const float* w0   = (const float*)d_in[4];
  const float* b0   = (const float*)d_in[5];
  const float* g0   = (const float*)d_in[6];
  const float* be0  = (const float*)d_in[7];
  const float* w1   = (const float*)d_in[8];
  const float* b1   = (const float*)d_in[9];
  const float* g1   = (const float*)d_in[10];
  const float* be1  = (const float*)d_in[11];
  const float* w2   = (const float*)d_in[12];
  const float* b2   = (const float*)d_in[13];
  const float* g2   = (const float*)d_in[14];
  const float* be2  = (const float*)d_in[15];
  const float* ow   = (const float*)d_in[16];
  const float* ob   = (const float*)d_in[17];

  const int N_  = in_sizes[3];
  const int E_  = in_sizes[2];
  const int DIN_= in_sizes[0] / N_;
  const int G_  = out_size;
  const int* srcIdx = ei;
  const int* dstIdx = ei + E_;
  const int n1 = N_ + 1;
  const size_t epad = (size_t)E_ + 7ull * N_;   // max padded edge slots

  float* ws = (float*)d_ws;
  size_t off = 0;
  uint2* elist    = (uint2*)(ws + off); off += 2 * epad;
  float* deg_dinv = ws + off; off += N_;
  float* sc       = ws + off; off += N_;
  int*   cnt      = (int*)(ws + off); off += N_;      // also cursor
  int*   rowstart = (int*)(ws + off); off += n1 + 1;
  int*   bsums    = (int*)(ws + off); off += 256;
  int*   gstart   = (int*)(ws + off); off += G_ + 1;
  __half* hhalf   = (__half*)(ws + off); off += (size_t)N_ * DH / 2;
  float* aggbuf   = ws + off; off += (size_t)N_ * DH;
  float* stats    = ws + off; off += 2 * DH;
  (void)ws_size; (void)n_in;

  // --- degree + histogram ---
  k_fill<<<(N_ + 255) / 256, 256, 0, stream>>>(deg_dinv, 1.0f, N_);
  k_fill<<<(N_ + 255) / 256, 256, 0, stream>>>((float*)cnt, 0.0f, N_);
  k_degcnt<<<(E_ + 255) / 256, 256, 0, stream>>>(dstIdx, ew, deg_dinv, cnt, E_);
  k_dinv<<<(N_ + 255) / 256, 256, 0, stream>>>(deg_dinv, sc, N_);

  // --- exclusive scan padded cnt -> rowstart ---
  const int nb = (n1 + 1023) / 1024;
  k_scan1<<<nb, 256, 0, stream>>>(cnt, rowstart, bsums, N_, n1);
  k_scan2<<<1, 256, 0, stream>>>(bsums, nb);
  k_scan3<<<(n1 + 255) / 256, 256, 0, stream>>>(rowstart, bsums, n1);

  // --- fill padded elist with (src=0, norm=0), then CSR reorder ---
  k_fill<<<(int)((2 * epad + 255) / 256), 256, 0, stream>>>((float*)elist, 0.0f, 2 * epad);
  k_fill<<<(N_ + 255) / 256, 256, 0, stream>>>((float*)cnt, 0.0f, N_);
  k_reorder<<<(E_ + 255) / 256, 256, 0, stream>>>(srcIdx, dstIdx, ew, deg_dinv,
                                                  rowstart, cnt, elist, E_);

  // --- graph boundaries for pooling ---
  k_gbound<<<(N_ + 255) / 256, 256, 0, stream>>>(batch, gstart, N_, G_);

  const float* Wl[3]  = {w0, w1, w2};
  const float* Bl[3]  = {b0, b1, b2};
  const float* Gl[3]  = {g0, g1, g2};
  const float* BeL[3] = {be0, be1, be2};

  const float invN = 1.0f / (float)N_;
  const float* curA = x;
  int curK = DIN_;

  for (int l = 0; l < 3; ++l) {
    // gemm l: A = (l==0 ? x : AGG(l-1) with BN(l-1)+ReLU fused), writes fp16 H
    k_gemm<<<(N_ + 127) / 128, 256, 0, stream>>>(
        curA, Wl[l], Bl[l], stats, (l ? Gl[l - 1] : nullptr),
        (l ? BeL[l - 1] : nullptr), hhalf, N_, curK, l ? 1 : 0, invN);
    k_fill<<<1, 256, 0, stream>>>(stats, 0.0f, 2 * DH);
    k_gather<<<2048, 256, 0, stream>>>(elist, rowstart, hhalf, sc, aggbuf, stats, N_);
    curA = aggbuf;
    curK = DH;
  }

  // --- fused BN2+ReLU+pooling+head ---
  k_poolhead<<<G_, 256, 0, stream>>>(aggbuf, stats, g2, be2, ow, gstart, ob,
                                     (float*)d_out, invN);
}

// Round 5
// 626.558 us; speedup vs baseline: 2.6269x; 1.1251x over previous
//
#include <hip/hip_runtime.h>
#include <hip/hip_fp16.h>
#include <cstdint>

#define DH 64
#define EPSV 1e-5f
#define NSHARD 8

__device__ __forceinline__ float atomAddF(float* p, float v) {
  return unsafeAtomicAdd(p, v);
}

__global__ void k_fill(float* __restrict__ p, float v, size_t n) {
  size_t i = blockIdx.x * (size_t)blockDim.x + threadIdx.x;
  if (i < n) p[i] = v;
}

// packed sharded histogram: one u64 atomic per edge.
// bits[40:63] = count, bits[0:39] = fixed-point (2^-24) sum of edge weights.
__global__ void k_hist(const int* __restrict__ dst, const float* __restrict__ ew,
                       unsigned long long* __restrict__ shard, int N_, int E_) {
  int e = blockIdx.x * blockDim.x + threadIdx.x;
  if (e < E_) {
    int q = dst[e];
    unsigned long long v =
        (1ull << 40) | (unsigned long long)(unsigned)(ew[e] * 16777216.0f);
    atomicAdd(&shard[(size_t)(blockIdx.x & (NSHARD - 1)) * N_ + q], v);
  }
}

// reduce shards -> cnt, dinv, sc  (deg includes +1 self-loop)
__global__ void k_redhist(const unsigned long long* __restrict__ shard,
                          int* __restrict__ cnt, float* __restrict__ dinv,
                          float* __restrict__ sc, int N_) {
  int i = blockIdx.x * blockDim.x + threadIdx.x;
  if (i < N_) {
    unsigned long long t = 0;
#pragma unroll
    for (int s = 0; s < NSHARD; ++s) t += shard[(size_t)s * N_ + i];
    float deg = 1.0f + (float)(t & 0xFFFFFFFFFFull) * (1.0f / 16777216.0f);
    cnt[i] = (int)(t >> 40);
    dinv[i] = rsqrtf(deg);
    sc[i] = 1.0f / deg;
  }
}

// ---- exclusive scan over n1 = N+1 values; value(i) = i<N ? pad8(cnt[i]) : 0 ----
__global__ __launch_bounds__(256) void k_scan1(const int* __restrict__ cnt,
                                               int* __restrict__ out,
                                               int* __restrict__ bsums,
                                               int N_, int n1) {
  __shared__ int sm[256];
  const int t = threadIdx.x;
  const int base = blockIdx.x * 1024 + t * 4;
  int v[4], lsum = 0;
#pragma unroll
  for (int j = 0; j < 4; ++j) {
    int i = base + j;
    v[j] = (i < N_) ? ((cnt[i] + 7) & ~7) : 0;   // pad rows to multiple of 8
    lsum += v[j];
  }
  sm[t] = lsum;
  __syncthreads();
  for (int o = 1; o < 256; o <<= 1) {
    int x = (t >= o) ? sm[t - o] : 0;
    __syncthreads();
    if (t >= o) sm[t] += x;
    __syncthreads();
  }
  int run = sm[t] - lsum;
#pragma unroll
  for (int j = 0; j < 4; ++j) {
    int i = base + j;
    if (i < n1) out[i] = run;
    run += v[j];
  }
  if (t == 255) bsums[blockIdx.x] = sm[255];
}

__global__ __launch_bounds__(256) void k_scan2(int* __restrict__ bsums, int nb) {
  __shared__ int sm[256];
  int t = threadIdx.x;
  int v = (t < nb) ? bsums[t] : 0;
  sm[t] = v;
  __syncthreads();
  for (int o = 1; o < 256; o <<= 1) {
    int x = (t >= o) ? sm[t - o] : 0;
    __syncthreads();
    if (t >= o) sm[t] += x;
    __syncthreads();
  }
  if (t < nb) bsums[t] = sm[t] - v;
}

__global__ void k_scan3(int* __restrict__ out, const int* __restrict__ bsums, int n1) {
  int i = blockIdx.x * blockDim.x + threadIdx.x;
  if (i < n1) out[i] += bsums[i >> 10];
}

// write (0,0) into pad slots only: [rowstart[i]+cnt[i], rowstart[i+1])
__global__ void k_padfill(const int* __restrict__ rowstart, const int* __restrict__ cnt,
                          uint2* __restrict__ elist, int N_) {
  int i = blockIdx.x * blockDim.x + threadIdx.x;
  if (i < N_) {
    int p = rowstart[i] + cnt[i], pe = rowstart[i + 1];
    for (; p < pe; ++p) elist[p] = make_uint2(0u, 0u);
  }
}

// CSR reorder, fusing the norm computation. elist[p] = (src, norm)
__global__ void k_reorder(const int* __restrict__ src, const int* __restrict__ dst,
                          const float* __restrict__ ew, const float* __restrict__ dinv,
                          const int* __restrict__ rowstart, int* __restrict__ cursor,
                          uint2* __restrict__ elist, int E_) {
  int e = blockIdx.x * blockDim.x + threadIdx.x;
  if (e < E_) {
    int s = src[e], q = dst[e];
    float nm = ew[e] * dinv[s] * dinv[q];
    int p = rowstart[q] + atomicAdd(&cursor[q], 1);
    elist[p] = make_uint2((unsigned)s, __float_as_uint(nm));
  }
}

// graph boundary detection on sorted batch: gstart[g] for g in [0,G]
__global__ void k_gbound(const int* __restrict__ batch, int* __restrict__ gstart,
                         int N_, int G_) {
  int i = blockIdx.x * blockDim.x + threadIdx.x;
  if (i >= N_) return;
  int b = batch[i];
  if (i == 0) {
    for (int g = 0; g <= b; ++g) gstart[g] = 0;
  }
  int nb = (i + 1 < N_) ? batch[i + 1] : G_;
  for (int g = b + 1; g <= nb; ++g) gstart[g] = i + 1;
}

// C tile 128 rows x 64 cols, 256 threads, micro-tile 4x8 per thread.
// Optionally applies BN(prev layer)+ReLU to A elements while loading.
// Epilogue writes fp16 H only.
__global__ __launch_bounds__(256) void k_gemm(
    const float* __restrict__ A, const float* __restrict__ W,
    const float* __restrict__ bias, const float* __restrict__ stats,
    const float* __restrict__ gam, const float* __restrict__ bet,
    __half* __restrict__ Hh, int n, int K, int fuse, float invN) {
  __shared__ float As[128][17];
  __shared__ float Bs[16][64];
  __shared__ float saL[DH], sbL[DH];
  const int tid = threadIdx.x;
  const int tx = tid & 7;
  const int ty = tid >> 3;
  const int r0 = blockIdx.x * 128;
  if (fuse && tid < DH) {
    float mean = stats[tid] * invN;
    float var = stats[DH + tid] * invN - mean * mean;
    float a = rsqrtf(var + EPSV) * gam[tid];
    saL[tid] = a;
    sbL[tid] = bet[tid] - mean * a;
  }
  if (fuse) __syncthreads();
  float acc[4][8] = {};
  for (int kc = 0; kc < K; kc += 16) {
    for (int idx = tid; idx < 128 * 16; idx += 256) {
      int r = idx >> 4, c = idx & 15;
      int gr = r0 + r, gc = kc + c;
      float v = (gr < n && gc < K) ? A[(size_t)gr * K + gc] : 0.0f;
      if (fuse) v = fmaxf(v * saL[gc] + sbL[gc], 0.0f);
      As[r][c] = v;
    }
    for (int idx = tid; idx < 16 * 64; idx += 256) {
      int r = idx >> 6, c = idx & 63;
      int gr = kc + r;
      Bs[r][c] = (gr < K) ? W[gr * DH + c] : 0.0f;
    }
    __syncthreads();
#pragma unroll
    for (int kk = 0; kk < 16; ++kk) {
      float a[4], b[8];
#pragma unroll
      for (int i = 0; i < 4; ++i) a[i] = As[ty * 4 + i][kk];
#pragma unroll
      for (int j = 0; j < 8; ++j) b[j] = Bs[kk][tx * 8 + j];
#pragma unroll
      for (int i = 0; i < 4; ++i)
#pragma unroll
        for (int j = 0; j < 8; ++j) acc[i][j] += a[i] * b[j];
    }
    __syncthreads();
  }
#pragma unroll
  for (int i = 0; i < 4; ++i) {
    int gr = r0 + ty * 4 + i;
    if (gr < n) {
      float h[8];
#pragma unroll
      for (int j = 0; j < 8; ++j) h[j] = acc[i][j] + bias[tx * 8 + j];
      uint4 o;
      o.x = (unsigned)__half_as_ushort(__float2half(h[0])) |
            ((unsigned)__half_as_ushort(__float2half(h[1])) << 16);
      o.y = (unsigned)__half_as_ushort(__float2half(h[2])) |
            ((unsigned)__half_as_ushort(__float2half(h[3])) << 16);
      o.z = (unsigned)__half_as_ushort(__float2half(h[4])) |
            ((unsigned)__half_as_ushort(__float2half(h[5])) << 16);
      o.w = (unsigned)__half_as_ushort(__float2half(h[6])) |
            ((unsigned)__half_as_ushort(__float2half(h[7])) << 16);
      *reinterpret_cast<uint4*>(&Hh[(size_t)gr * DH + tx * 8]) = o;
    }
  }
}

// Pull aggregation: one wave per dst row (grid-stride), lane d = feature d.
// Rows padded to multiples of 8 edges -> tail-free, 8 gathers in flight.
__global__ __launch_bounds__(256) void k_gather(
    const uint2* __restrict__ elist, const int* __restrict__ rowstart,
    const __half* __restrict__ Hh, const float* __restrict__ sc,
    float* __restrict__ AGG, float* __restrict__ stats, int n) {
  const int wid = threadIdx.x >> 6;
  const int d = threadIdx.x & 63;
  const int gw = blockIdx.x * 4 + wid;
  const int nw = gridDim.x * 4;
  float s = 0.f, ss = 0.f;
  for (int row = gw; row < n; row += nw) {
    int rs = rowstart[row], re = rowstart[row + 1];
    float acc = __half2float(Hh[(size_t)row * DH + d]) * sc[row];
    for (int i = rs; i < re; i += 8) {
      uint2 e[8];
#pragma unroll
      for (int j = 0; j < 8; ++j) e[j] = elist[i + j];
      float v[8];
#pragma unroll
      for (int j = 0; j < 8; ++j)
        v[j] = __half2float(Hh[(size_t)e[j].x * DH + d]);
#pragma unroll
      for (int j = 0; j < 8; ++j)
        acc = fmaf(__uint_as_float(e[j].y), v[j], acc);
    }
    AGG[(size_t)row * DH + d] = acc;
    s += acc;
    ss += acc * acc;
  }
  __shared__ float sm[4][DH], sm2[4][DH];
  sm[wid][d] = s;
  sm2[wid][d] = ss;
  __syncthreads();
  if (threadIdx.x < DH) {
    float a = sm[0][d] + sm[1][d] + sm[2][d] + sm[3][d];
    float b = sm2[0][d] + sm2[1][d] + sm2[2][d] + sm2[3][d];
    atomAddF(&stats[d], a);
    atomAddF(&stats[DH + d], b);
  }
}

// fused BN+ReLU+mean-pool+head: one block per graph.
__global__ __launch_bounds__(256) void k_poolhead(
    const float* __restrict__ AGG, const float* __restrict__ stats,
    const float* __restrict__ gam, const float* __restrict__ bet,
    const float* __restrict__ ow, const int* __restrict__ gstart,
    const float* __restrict__ ob, float* __restrict__ out, float invN) {
  const int g = blockIdx.x;
  const int gs = gstart[g], ge = gstart[g + 1];
  const int wid = threadIdx.x >> 6;
  const int d = threadIdx.x & 63;
  float mean = stats[d] * invN;
  float var = stats[DH + d] * invN - mean * mean;
  float sa = rsqrtf(var + EPSV) * gam[d];
  float sb = bet[d] - mean * sa;
  const float w = ow[d];
  float acc = 0.f;
  for (int row = gs + wid; row < ge; row += 4)
    acc += fmaxf(AGG[(size_t)row * DH + d] * sa + sb, 0.f) * w;
#pragma unroll
  for (int off = 32; off > 0; off >>= 1) acc += __shfl_down(acc, off, 64);
  __shared__ float sm[4];
  if (d == 0) sm[wid] = acc;
  __syncthreads();
  if (threadIdx.x == 0) {
    float s = sm[0] + sm[1] + sm[2] + sm[3];
    float cnt = (float)(ge - gs);
    out[g] = s / fmaxf(cnt, 1.0f) + ob[0];
  }
}

extern "C" void kernel_launch(void* const* d_in, const int* in_sizes, int n_in,
                              void* d_out, int out_size, void* d_ws, size_t ws_size,
                              hipStream_t stream) {
  const float* x    = (const float*)d_in[0];
  const int*   ei   = (const int*)d_in[1];
  const float* ew   = (const float*)d_in[2];
  const int*   batch= (const int*)d_in[3];
  const float* w0   = (const float*)d_in[4];
  const float* b0   = (const float*)d_in[5];
  const float* g0   = (const float*)d_in[6];
  const float* be0  = (const float*)d_in[7];
  const float* w1   = (const float*)d_in[8];
  const float* b1   = (const float*)d_in[9];
  const float* g1   = (const float*)d_in[10];
  const float* be1  = (const float*)d_in[11];
  const float* w2   = (const float*)d_in[12];
  const float* b2   = (const float*)d_in[13];
  const float* g2   = (const float*)d_in[14];
  const float* be2  = (const float*)d_in[15];
  const float* ow   = (const float*)d_in[16];
  const float* ob   = (const float*)d_in[17];

  const int N_  = in_sizes[3];
  const int E_  = in_sizes[2];
  const int DIN_= in_sizes[0] / N_;
  const int G_  = out_size;
  const int* srcIdx = ei;
  const int* dstIdx = ei + E_;
  const int n1 = N_ + 1;
  const size_t epad = (size_t)E_ + 7ull * N_;   // max padded edge slots

  float* ws = (float*)d_ws;
  size_t off = 0;
  uint2* elist    = (uint2*)(ws + off); off += 2 * epad;
  unsigned long long* shard = (unsigned long long*)(ws + off); off += (size_t)2 * NSHARD * N_;
  float* dinv     = ws + off; off += N_;
  float* sc       = ws + off; off += N_;
  int*   cnt      = (int*)(ws + off); off += N_;
  int*   cursor   = (int*)(ws + off); off += N_;
  int*   rowstart = (int*)(ws + off); off += n1 + 1;
  int*   bsums    = (int*)(ws + off); off += 256;
  int*   gstart   = (int*)(ws + off); off += G_ + 1;
  __half* hhalf   = (__half*)(ws + off); off += (size_t)N_ * DH / 2;
  float* aggbuf   = ws + off; off += (size_t)N_ * DH;
  float* stats    = ws + off; off += 2 * DH;
  (void)ws_size; (void)n_in;

  // --- packed sharded histogram ---
  k_fill<<<(int)(((size_t)2 * NSHARD * N_ + 255) / 256), 256, 0, stream>>>(
      (float*)shard, 0.0f, (size_t)2 * NSHARD * N_);
  k_hist<<<(E_ + 255) / 256, 256, 0, stream>>>(dstIdx, ew, shard, N_, E_);
  k_redhist<<<(N_ + 255) / 256, 256, 0, stream>>>(shard, cnt, dinv, sc, N_);

  // --- exclusive scan padded cnt -> rowstart ---
  const int nb = (n1 + 1023) / 1024;
  k_scan1<<<nb, 256, 0, stream>>>(cnt, rowstart, bsums, N_, n1);
  k_scan2<<<1, 256, 0, stream>>>(bsums, nb);
  k_scan3<<<(n1 + 255) / 256, 256, 0, stream>>>(rowstart, bsums, n1);

  // --- pad slots + CSR reorder ---
  k_padfill<<<(N_ + 255) / 256, 256, 0, stream>>>(rowstart, cnt, elist, N_);
  k_fill<<<(N_ + 255) / 256, 256, 0, stream>>>((float*)cursor, 0.0f, N_);
  k_reorder<<<(E_ + 255) / 256, 256, 0, stream>>>(srcIdx, dstIdx, ew, dinv,
                                                  rowstart, cursor, elist, E_);

  // --- graph boundaries for pooling ---
  k_gbound<<<(N_ + 255) / 256, 256, 0, stream>>>(batch, gstart, N_, G_);

  const float* Wl[3]  = {w0, w1, w2};
  const float* Bl[3]  = {b0, b1, b2};
  const float* Gl[3]  = {g0, g1, g2};
  const float* BeL[3] = {be0, be1, be2};

  const float invN = 1.0f / (float)N_;
  const float* curA = x;
  int curK = DIN_;

  for (int l = 0; l < 3; ++l) {
    k_gemm<<<(N_ + 127) / 128, 256, 0, stream>>>(
        curA, Wl[l], Bl[l], stats, (l ? Gl[l - 1] : nullptr),
        (l ? BeL[l - 1] : nullptr), hhalf, N_, curK, l ? 1 : 0, invN);
    k_fill<<<1, 256, 0, stream>>>(stats, 0.0f, 2 * DH);
    k_gather<<<2048, 256, 0, stream>>>(elist, rowstart, hhalf, sc, aggbuf, stats, N_);
    curA = aggbuf;
    curK = DH;
  }

  // --- fused BN2+ReLU+pooling+head ---
  k_poolhead<<<G_, 256, 0, stream>>>(aggbuf, stats, g2, be2, ow, gstart, ob,
                                     (float*)d_out, invN);
}